// Round 2
// 248.836 us; speedup vs baseline: 1.0391x; 1.0391x over previous
//
#include <hip/hip_runtime.h>

typedef unsigned short u16;
typedef __attribute__((ext_vector_type(8))) __bf16 bf16x8;
typedef __attribute__((ext_vector_type(8))) short short8;
typedef __attribute__((ext_vector_type(4))) short short4v;
typedef __attribute__((ext_vector_type(4))) float floatx4;

__device__ __forceinline__ u16 f2bf(float f){
  unsigned int x = __float_as_uint(f);
  unsigned int r = (x + 0x7fffu + ((x >> 16) & 1u)) >> 16;  // RTNE
  return (u16)r;
}

// async 16B global->LDS copy; lds base must be wave-uniform (HW: base + lane*16)
#define GLL(g, l) __builtin_amdgcn_global_load_lds( \
    (const __attribute__((address_space(1))) void*)(g), \
    (__attribute__((address_space(3))) void*)(l), 16, 0, 0)

// ============================ PREP PASS =====================================
// blocks 0..1023: x[b][ci][t][y][zw] fp32 -> xp[b][t][y][zw][ci] bf16,
//   16B chunks XOR-placed: chunk position p holds ci-oct (p ^ (zw&7)).
//   v2: LDS-staged transpose. Phase A: float4 reads (1 KB contiguous per
//   wave-instr, one full ci-row per instruction), convert, b64 LDS writes into
//   a bank-swizzled [ci][zw-granule] buffer. Phase B: gather 8 ci per output
//   chunk from LDS, store b128 fully coalesced (1 KB contiguous per wave-instr).
// blocks 1024..2319: weight fp32 -> wp[tap][kc][co][ci32] bf16 (unchanged).
__global__ void prep_kernel(const float* __restrict__ x, const float* __restrict__ w,
                            u16* __restrict__ xp, u16* __restrict__ wp){
  __shared__ __attribute__((aligned(16))) u16 I[16384];  // 32 KB: [ci][granule] swizzled
  const int bx = blockIdx.x;
  const int tid = threadIdx.x;
  if (bx < 1024){
    const int y = bx & 15, t = (bx >> 4) & 15, b = bx >> 8;
    const int l  = tid & 63;   // lane
    const int wv = tid >> 6;   // wave
    const float* xb = x + (size_t)b*64*65536 + t*4096 + y*256;

    // ---- Phase A: read + convert + swizzled LDS write ----
    // wave wv handles ci = 4j + wv; lane l covers zw = 4l..4l+3 (one float4).
#pragma unroll
    for (int j = 0; j < 16; ++j){
      const int ci = j*4 + wv;
      const float4 f = *(const float4*)(xb + (size_t)ci*65536 + l*4);
      const int o  = ci >> 3;
      const int gp = l ^ o ^ ((o & 1) << 3);     // granule swizzle (bijective per ci)
      short4v hv;
      hv[0] = (short)f2bf(f.x);
      hv[1] = (short)f2bf(f.y);
      hv[2] = (short)f2bf(f.z);
      hv[3] = (short)f2bf(f.w);
      *(short4v*)(I + ci*256 + gp*4) = hv;       // b64, 8B aligned
    }
    __syncthreads();

    // ---- Phase B: gather + coalesced b128 global store ----
    // thread tid stores the 16B chunk at byte (it*4096 + tid*16) of the plane:
    //   row zw = it*32 + (tid>>3), chunk position p = tid&7, oct o = p ^ (zw&7).
    const int p  = tid & 7;
    const int r0 = tid >> 3;
    u16* dst = xp + (size_t)bx*16384;
#pragma unroll
    for (int it = 0; it < 8; ++it){
      const int zw = it*32 + r0;
      const int o  = p ^ (zw & 7);
      const int g  = zw >> 2;
      const int gp = g ^ o ^ ((o & 1) << 3);
      const int base = gp*4 + (zw & 3);
      short8 vv;
#pragma unroll
      for (int m = 0; m < 8; ++m)
        vv[m] = (short)I[(o*8 + m)*256 + base];
      *(short8*)(dst + it*2048 + tid*8) = vv;    // 1 KB contiguous per wave-instr
    }
  } else {
    int idx = (bx - 1024)*256 + tid;   // linear over w input (coalesced)
    if (idx < 81*64*64){
      int r  = idx;
      int dw = r % 3; r /= 3;
      int dz = r % 3; r /= 3;
      int dy = r % 3; r /= 3;
      int ci = r & 63; r >>= 6;
      int co = r & 63; r >>= 6;
      int dt = r;
      int tap = ((dt*3 + dy)*3 + dz)*3 + dw;
      int kc = ci >> 5, ci32 = ci & 31;
      wp[tap*4096 + kc*2048 + co*32 + ci32] = f2bf(w[idx]);
    }
  }
}

// ============================ MAIN KERNEL ===================================
// (unchanged — isolates the prep change)
__global__ __launch_bounds__(256, 2) void conv4d_mfma_v4(
    const u16* __restrict__ xp, const u16* __restrict__ wp,
    const float* __restrict__ bias, float* __restrict__ out)
{
  __shared__ __attribute__((aligned(16))) u16 x_lds[16384];     // [zw][ci], XOR chunks
  __shared__ __attribute__((aligned(16))) u16 a_lds[2][12288];  // [dw][kc][co][ci32] x2

  const int bx = blockIdx.x;
  const int c = bx & 7, j = bx >> 3;
  const int b = c >> 1, t = j >> 3, y = (c & 1)*8 + (j & 7);

  const int tid  = threadIdx.x;
  const int lane = tid & 63;
  const int wv   = tid >> 6;
  const int wl   = lane & 15;   // B: n (w-pos); A: m (co row within 16-tile)
  const int q    = lane >> 4;   // k-octet selector; D: co = quad*4+reg

  floatx4 acc[4][4];
#pragma unroll
  for (int zi = 0; zi < 4; ++zi)
#pragma unroll
    for (int mi = 0; mi < 4; ++mi)
      acc[zi][mi] = (floatx4)0.0f;

  auto stage_x = [&](int dtdy){
    const int dt = dtdy / 3, dy = dtdy % 3;
    const int tt = (t + dt + 15) & 15;
    const int yy = (y + dy + 15) & 15;
    const u16* plane = xp + (size_t)(((b*16 + tt)*16) + yy) * 16384;
#pragma unroll
    for (int i = 0; i < 8; ++i)
      GLL(plane + wv*4096 + i*512 + lane*8, x_lds + wv*4096 + i*512);
  };
  auto stage_a = [&](int s, int buf){
    const int dtdy = s / 3, dz = s % 3;
    const int tap0 = ((dtdy/3)*9 + (dtdy%3)*3 + dz)*3;   // ((dt*3+dy)*3+dz)*3
    const u16* asrc = wp + (size_t)tap0 * 4096;          // 3 taps, 24 KB contiguous
#pragma unroll
    for (int i = 0; i < 6; ++i)
      GLL(asrc + wv*3072 + i*512 + lane*8, a_lds[buf] + wv*3072 + i*512);
  };

  // prologue
  stage_x(0);
  stage_a(0, 0);
  __syncthreads();   // drain: x plane 0 + a slab 0 ready

  for (int s = 0; s < 27; ++s){
    const int dz  = s % 3;
    const int cur = s & 1;
    const bool boundary = (dz == 2);        // next s starts a new (dt,dy)
    if (s + 1 < 27 && !boundary)
      stage_a(s + 1, cur ^ 1);              // async prefetch, overlaps MFMAs below

    // ---- compute slab s: 96 MFMAs
    const u16* ab = a_lds[cur];
#pragma unroll
    for (int dw = 0; dw < 3; ++dw){
      const int ww = (wl + dw + 15) & 15;
      const int wx = ww & 7;
#pragma unroll
      for (int kc = 0; kc < 2; ++kc){
        bf16x8 af[4];
#pragma unroll
        for (int mi = 0; mi < 4; ++mi)
          af[mi] = *(const bf16x8*)(ab + ((dw*2 + kc)*64 + mi*16 + wl)*32 + q*8);
        const int chunk = ((kc*4 + q) ^ wx)*8;
#pragma unroll
        for (int zi = 0; zi < 4; ++zi){
          const int zz = (wv*4 + zi + dz + 15) & 15;
          bf16x8 bf = *(const bf16x8*)(x_lds + (zz*16 + ww)*64 + chunk);
#pragma unroll
          for (int mi = 0; mi < 4; ++mi)
            acc[zi][mi] = __builtin_amdgcn_mfma_f32_16x16x32_bf16(af[mi], bf, acc[zi][mi], 0, 0, 0);
        }
      }
    }

    if (s + 1 >= 27) break;
    if (boundary){
      __syncthreads();                      // compute done: x_lds + both a bufs free
      stage_x(s/3 + 1);
      stage_a(s + 1, cur ^ 1);
      __syncthreads();                      // drain x + a for next iteration
    } else {
      __syncthreads();                      // a slab s+1 visible (vmcnt already ~drained)
    }
  }

  // ---- epilogue: bias + fp32 store
  float bvals[4][4];
#pragma unroll
  for (int mi = 0; mi < 4; ++mi)
#pragma unroll
    for (int r = 0; r < 4; ++r)
      bvals[mi][r] = bias[mi*16 + q*4 + r];

  float* ob = out + (size_t)b*64*65536 + t*4096 + y*256 + wl;
#pragma unroll
  for (int zi = 0; zi < 4; ++zi){
    const int z = wv*4 + zi;
#pragma unroll
    for (int mi = 0; mi < 4; ++mi){
#pragma unroll
      for (int r = 0; r < 4; ++r){
        const int co = mi*16 + q*4 + r;   // C/D: row = quad*4 + reg
        ob[(size_t)co*65536 + z*16] = acc[zi][mi][r] + bvals[mi][r];
      }
    }
  }
}

// ===================== FALLBACK (round-2 proven path) =======================
__global__ void repack_w_kernel(const float* __restrict__ w, u16* __restrict__ wp){
  int idx = blockIdx.x * 256 + threadIdx.x;
  if (idx >= 81*64*64) return;
  int cw  = idx & 31;
  int t1  = idx >> 5;
  int co  = t1 & 63; t1 >>= 6;
  int kc  = t1 & 1;  t1 >>= 1;
  int tap = t1;
  int dw = tap % 3, dz = (tap/3) % 3, dy = (tap/9) % 3, dt = tap/27;
  int ci = kc*32 + cw;
  int in_idx = ((((dt*64 + co)*64 + ci)*3 + dy)*3 + dz)*3 + dw;
  wp[idx] = f2bf(w[in_idx]);
}

__global__ __launch_bounds__(256, 2) void conv4d_mfma_kernel(
    const float* __restrict__ x, const u16* __restrict__ wp,
    const float* __restrict__ bias, float* __restrict__ out)
{
  __shared__ __attribute__((aligned(16))) u16 x_lds[256*72];
  __shared__ __attribute__((aligned(16))) u16 a_lds[3*2*64*32];
  const int bx = blockIdx.x;
  const int y = bx & 15, t = (bx >> 4) & 15, b = bx >> 8;
  const int tid  = threadIdx.x;
  const int lane = tid & 63;
  const int wv   = tid >> 6;
  const int wl   = lane & 15;
  const int q    = lane >> 4;
  floatx4 acc[4][4];
#pragma unroll
  for (int zi = 0; zi < 4; ++zi)
#pragma unroll
    for (int mi = 0; mi < 4; ++mi)
      acc[zi][mi] = (floatx4)0.0f;
  const float* xb = x + (size_t)b * 64 * 65536;
  for (int dt = 0; dt < 3; ++dt){
    const int tt = (t + dt + 15) & 15;
    for (int dy = 0; dy < 3; ++dy){
      const int yy = (y + dy + 15) & 15;
      __syncthreads();
      {
        const float* src = xb + tt*4096 + yy*256 + tid;
#pragma unroll
        for (int oct = 0; oct < 8; ++oct){
          float v[8];
#pragma unroll
          for (int j = 0; j < 8; ++j)
            v[j] = src[(size_t)(oct*8 + j) * 65536];
          short8 vv;
#pragma unroll
          for (int j = 0; j < 8; ++j) vv[j] = (short)f2bf(v[j]);
          *(short8*)(x_lds + tid*72 + oct*8) = vv;
        }
      }
      for (int dz = 0; dz < 3; ++dz){
        const int tap0 = ((dt*3 + dy)*3 + dz)*3;
        __syncthreads();
        {
          const u16* asrc = wp + (size_t)tap0 * 4096;
#pragma unroll
          for (int i = 0; i < 6; ++i){
            int e = (i*256 + tid) * 8;
            *(short8*)(a_lds + e) = *(const short8*)(asrc + e);
          }
        }
        __syncthreads();
#pragma unroll
        for (int dw = 0; dw < 3; ++dw){
          const int ww = (wl + dw + 15) & 15;
#pragma unroll
          for (int kc = 0; kc < 2; ++kc){
            bf16x8 af[4];
#pragma unroll
            for (int mi = 0; mi < 4; ++mi)
              af[mi] = *(const bf16x8*)(a_lds + ((dw*2 + kc)*64 + mi*16 + wl)*32 + q*8);
#pragma unroll
            for (int zi = 0; zi < 4; ++zi){
              const int zz = (wv*4 + zi + dz + 15) & 15;
              bf16x8 bf = *(const bf16x8*)(x_lds + (zz*16 + ww)*72 + kc*32 + q*8);
#pragma unroll
              for (int mi = 0; mi < 4; ++mi)
                acc[zi][mi] = __builtin_amdgcn_mfma_f32_16x16x32_bf16(af[mi], bf, acc[zi][mi], 0, 0, 0);
            }
          }
        }
      }
    }
  }
  float bvals[4][4];
#pragma unroll
  for (int mi = 0; mi < 4; ++mi)
#pragma unroll
    for (int r = 0; r < 4; ++r)
      bvals[mi][r] = bias[mi*16 + q*4 + r];
  float* ob = out + (size_t)b * 64 * 65536 + t*4096 + y*256 + wl;
#pragma unroll
  for (int zi = 0; zi < 4; ++zi){
    const int z = wv*4 + zi;
#pragma unroll
    for (int mi = 0; mi < 4; ++mi){
#pragma unroll
      for (int r = 0; r < 4; ++r){
        const int co = mi*16 + q*4 + r;
        ob[(size_t)co*65536 + z*16] = acc[zi][mi][r] + bvals[mi][r];
      }
    }
  }
}

extern "C" void kernel_launch(void* const* d_in, const int* in_sizes, int n_in,
                              void* d_out, int out_size, void* d_ws, size_t ws_size,
                              hipStream_t stream) {
  const float* x    = (const float*)d_in[0];
  const float* w    = (const float*)d_in[1];
  const float* bias = (const float*)d_in[2];
  float* out = (float*)d_out;

  const size_t xp_bytes = (size_t)1024 * 16384 * 2;   // 33.55 MB bf16 transposed x
  const size_t wp_bytes = 81*64*64*2;                  // 663.5 KB packed weights
  if (ws_size >= xp_bytes + wp_bytes){
    u16* xp = (u16*)d_ws;
    u16* wp = (u16*)((char*)d_ws + xp_bytes);
    prep_kernel<<<1024 + 1296, 256, 0, stream>>>(x, w, xp, wp);
    conv4d_mfma_v4<<<1024, 256, 0, stream>>>(xp, wp, bias, out);
  } else {
    u16* wp = (u16*)d_ws;
    repack_w_kernel<<<1296, 256, 0, stream>>>(w, wp);
    conv4d_mfma_kernel<<<1024, 256, 0, stream>>>(x, wp, bias, out);
  }
}